// Round 1
// baseline (7742.422 us; speedup 1.0000x reference)
//
#include <hip/hip_runtime.h>
#include <cmath>

#define B_ 16
#define S_ 2048
#define N_ 3
#define E_ 128
#define V_ 50000
#define L_ 12
#define KW 3
#define LYR_ 5
#define W_ 384
#define TW_ 768

#define BI 32
#define BS 64

static constexpr float GM_ = 1.0f / 6.0f;          // 1/(2*ATTN_LAYERS)
static constexpr float SQRT_HALF_ = 0.7071067811865476f;

// ---------------------------------------------------------------------------
// Kernel 1: weight-norm scale.  scale[l,k] = conv_g[l,k] / sqrt(sum_{o,i} v^2)
// (mathematically ==1.0 given setup, but compute exactly for bit-closeness)
// ---------------------------------------------------------------------------
__global__ void scale_kernel(const float* __restrict__ v,
                             const float* __restrict__ g,
                             float* __restrict__ scale) {
  int layer = blockIdx.x / KW, k = blockIdx.x % KW;
  const float* vp = v + (size_t)layer * TW_ * W_ * KW + k;
  float acc = 0.f;
  for (int idx = threadIdx.x; idx < TW_ * W_; idx += blockDim.x) {
    float x = vp[(size_t)idx * KW];
    acc += x * x;
  }
  for (int off = 32; off > 0; off >>= 1) acc += __shfl_down(acc, off, 64);
  __shared__ float red[4];
  int lane = threadIdx.x & 63, wv = threadIdx.x >> 6;
  if (lane == 0) red[wv] = acc;
  __syncthreads();
  if (threadIdx.x == 0) {
    float s = red[0] + red[1] + red[2] + red[3];
    scale[blockIdx.x] = g[blockIdx.x] / sqrtf(s);
  }
}

// ---------------------------------------------------------------------------
// Kernel 2: embedding.  Produces e (== h0) in (B, W, S) layout, written to
// both the ws h-buffer (conv input) and the `e` half of d_out.
// Block: 384 threads (one per w), 32 s-positions per block, LDS transpose
// so global writes are s-contiguous.
// ---------------------------------------------------------------------------
__global__ __launch_bounds__(384) void embed_kernel(
    const int* __restrict__ x, const int* __restrict__ ngram_ids,
    const int* __restrict__ ngram_counts, const float* __restrict__ emb0,
    const float* __restrict__ tables, float* __restrict__ h0,
    float* __restrict__ e_out) {
  __shared__ float tile[W_][33];
  int b = blockIdx.y;
  int s0 = blockIdx.x * 32;
  int w = threadIdx.x;  // 0..383
  int n = w >> 7, t = w & 127;
  const float* tab = tables + (size_t)n * (V_ + 1) * E_ + t;

  for (int sl = 0; sl < 32; ++sl) {
    int s = s0 + sl;
    int xv = x[b * S_ + s];
    float val;
    if (xv < 4) {
      val = emb0[xv * W_ + w];
    } else {
      int base = (b * S_ + s) * N_ + n;
      int cnt = ngram_counts[base];
      const int* ids = ngram_ids + (size_t)base * L_;
      float acc = 0.f;
      for (int l = 0; l < cnt; ++l) {
        int id = ids[l];
        acc += tab[(size_t)id * E_];
      }
      val = acc / (float)cnt;
    }
    tile[w][sl] = val;
  }
  __syncthreads();
  for (int idx = threadIdx.x; idx < W_ * 32; idx += 384) {
    int wr = idx >> 5, sl = idx & 31;
    float vv = tile[wr][sl];
    size_t o = ((size_t)b * W_ + wr) * S_ + s0 + sl;
    h0[o] = vv;
    e_out[o] = vv;
  }
}

// ---------------------------------------------------------------------------
// Kernel 3: fused conv1d (K=3, pad 1) + bias + GLU + gm-no-op + residual.
// Input  hin  (B, W, S), weights v (2W, W, K) [layer slice], output hout.
// Block computes a 64(o-rows)x64(s) y-tile where rows 0..31 are GLU 'a'
// rows [o0, o0+32) and rows 32..63 are their gates [384+o0, 384+o0+32).
// 256 threads, 4x4 register micro-tile, BI=32 i-staging.
// ---------------------------------------------------------------------------
__global__ __launch_bounds__(256, 4) void conv_glu_kernel(
    const float* __restrict__ hin, float* __restrict__ hout,
    const float* __restrict__ v, const float* __restrict__ bias,
    const float* __restrict__ scale3) {
  __shared__ union {
    struct {
      float wl[BI][KW][64];
      float hl[BI][BS + 2];
    } a;
    float yt[64][BS];
  } sm;

  const int b = blockIdx.z;
  const int o0 = blockIdx.y * 32;
  const int s0 = blockIdx.x * BS;
  const int tid = threadIdx.x;
  const int tx = tid & 15;   // s-group (4 s each)
  const int ty = tid >> 4;   // o-group (4 o each), 16 groups = 64 rows

  const float sc0 = scale3[0], sc1 = scale3[1], sc2 = scale3[2];

  float acc[4][4] = {};

  for (int i0 = 0; i0 < W_; i0 += BI) {
    if (i0) __syncthreads();
    // stage weights: wl[ii][k][r], r<32 -> row o0+r ; r>=32 -> row 352+o0+r
    for (int idx = tid; idx < BI * KW * 64; idx += 256) {
      int r = idx & 63;
      int kk = (idx >> 6) % KW;
      int ii = idx / (64 * KW);
      int og = (r < 32) ? (o0 + r) : (352 + o0 + r);
      float sck = (kk == 0) ? sc0 : (kk == 1 ? sc1 : sc2);
      sm.a.wl[ii][kk][r] = v[(size_t)og * (W_ * KW) + (i0 + ii) * KW + kk] * sck;
    }
    // stage input rows with halo (zero padded)
    for (int idx = tid; idx < BI * (BS + 2); idx += 256) {
      int c = idx % (BS + 2);
      int ii = idx / (BS + 2);
      int s = s0 + c - 1;
      float hv = (s >= 0 && s < S_)
                     ? hin[((size_t)b * W_ + i0 + ii) * S_ + s]
                     : 0.f;
      sm.a.hl[ii][c] = hv;
    }
    __syncthreads();

#pragma unroll 4
    for (int ii = 0; ii < BI; ++ii) {
      float hr[6];
#pragma unroll
      for (int c = 0; c < 6; ++c) hr[c] = sm.a.hl[ii][tx * 4 + c];
      float wv_[KW][4];
      *(float4*)wv_[0] = *(const float4*)&sm.a.wl[ii][0][ty * 4];
      *(float4*)wv_[1] = *(const float4*)&sm.a.wl[ii][1][ty * 4];
      *(float4*)wv_[2] = *(const float4*)&sm.a.wl[ii][2][ty * 4];
#pragma unroll
      for (int oo = 0; oo < 4; ++oo) {
#pragma unroll
        for (int ss = 0; ss < 4; ++ss) {
          float tacc = acc[oo][ss];
          tacc = fmaf(wv_[0][oo], hr[ss], tacc);
          tacc = fmaf(wv_[1][oo], hr[ss + 1], tacc);
          tacc = fmaf(wv_[2][oo], hr[ss + 2], tacc);
          acc[oo][ss] = tacc;
        }
      }
    }
  }
  __syncthreads();

  // exchange y tile through LDS for the GLU pairing
#pragma unroll
  for (int oo = 0; oo < 4; ++oo)
#pragma unroll
    for (int ss = 0; ss < 4; ++ss)
      sm.yt[ty * 4 + oo][tx * 4 + ss] = acc[oo][ss];
  __syncthreads();

  for (int idx = tid; idx < 32 * BS; idx += 256) {
    int r = idx >> 6;     // 0..31
    int c = idx & (BS - 1);
    float av = sm.yt[r][c] + bias[o0 + r];
    float gv = sm.yt[32 + r][c] + bias[384 + o0 + r];
    float yy = av / (1.f + expf(-gv));
    yy = yy * GM_ + yy * (1.0f - GM_);
    size_t off = ((size_t)b * W_ + o0 + r) * S_ + s0 + c;
    hout[off] = (yy + hin[off]) * SQRT_HALF_;
  }
}

// ---------------------------------------------------------------------------
extern "C" void kernel_launch(void* const* d_in, const int* in_sizes, int n_in,
                              void* d_out, int out_size, void* d_ws,
                              size_t ws_size, hipStream_t stream) {
  const int* x = (const int*)d_in[0];
  const int* ngram_ids = (const int*)d_in[1];
  const int* ngram_counts = (const int*)d_in[2];
  const float* emb0 = (const float*)d_in[3];
  const float* tables = (const float*)d_in[4];
  const float* conv_v = (const float*)d_in[5];
  const float* conv_g = (const float*)d_in[6];
  const float* conv_b = (const float*)d_in[7];

  float* out_h = (float*)d_out;                       // (B, W, S)
  float* out_e = out_h + (size_t)B_ * W_ * S_;        // (B, W, S)

  float* ws_scale = (float*)d_ws;                     // 15 floats (+pad)
  float* wsH = ws_scale + 64;                         // (B, W, S) scratch h

  // 1. weight-norm scales
  scale_kernel<<<LYR_ * KW, 256, 0, stream>>>(conv_v, conv_g, ws_scale);

  // 2. embedding -> h0 (ws) and e (d_out)
  embed_kernel<<<dim3(S_ / 32, B_), 384, 0, stream>>>(
      x, ngram_ids, ngram_counts, emb0, tables, wsH, out_e);

  // 3. conv stack, ping-pong wsH <-> out_h; layer 4 (last) lands in out_h
  for (int l = 0; l < LYR_; ++l) {
    const float* hin = (l % 2 == 0) ? wsH : out_h;
    float* hout = (l % 2 == 0) ? out_h : wsH;
    const float* vl = conv_v + (size_t)l * TW_ * W_ * KW;
    const float* bl = conv_b + (size_t)l * TW_;
    const float* sl = ws_scale + l * KW;
    conv_glu_kernel<<<dim3(S_ / BS, W_ / 32, B_), 256, 0, stream>>>(
        hin, hout, vl, bl, sl);
  }
}

// Round 5
// 1505.907 us; speedup vs baseline: 5.1414x; 5.1414x over previous
//
#include <hip/hip_runtime.h>
#include <cmath>

#define B_ 16
#define S_ 2048
#define N_ 3
#define E_ 128
#define V_ 50000
#define L_ 12
#define KW 3
#define LYR_ 5
#define W_ 384
#define TW_ 768

static constexpr float GM_ = 1.0f / 6.0f;  // 1/(2*ATTN_LAYERS)
static constexpr float SQRT_HALF_ = 0.7071067811865476f;

typedef _Float16 half8 __attribute__((ext_vector_type(8)));
typedef float f32x4 __attribute__((ext_vector_type(4)));
typedef float f32x16 __attribute__((ext_vector_type(16)));

__device__ inline void gload_lds16(const void* g, void* l) {
  __builtin_amdgcn_global_load_lds(
      (const __attribute__((address_space(1))) void*)g,
      (__attribute__((address_space(3))) void*)l, 16, 0, 0);
}

// ---------------------------------------------------------------------------
// Kernel 1: weight-norm scale. scale[l*3+k] = g[l,k] / ||v[l,:,:,k]||
// ---------------------------------------------------------------------------
__global__ void scale_kernel(const float* __restrict__ v,
                             const float* __restrict__ g,
                             float* __restrict__ scale) {
  int layer = blockIdx.x / KW, k = blockIdx.x % KW;
  const float* vp = v + (size_t)layer * TW_ * W_ * KW + k;
  float acc = 0.f;
  for (int idx = threadIdx.x; idx < TW_ * W_; idx += blockDim.x) {
    float x = vp[(size_t)idx * KW];
    acc += x * x;
  }
  for (int off = 32; off > 0; off >>= 1) acc += __shfl_down(acc, off, 64);
  __shared__ float red[4];
  int lane = threadIdx.x & 63, wv = threadIdx.x >> 6;
  if (lane == 0) red[wv] = acc;
  __syncthreads();
  if (threadIdx.x == 0) {
    float s = red[0] + red[1] + red[2] + red[3];
    scale[blockIdx.x] = g[blockIdx.x] / sqrtf(s);
  }
}

// ---------------------------------------------------------------------------
// Kernel 2: bake per-layer weights into pre-swizzled f16 LDS images.
// Image (l, ob in 0..5, st in 0..11): 128 rows x 256B. Row r<64 -> 'a' row
// ob*64+r ; r>=64 -> gate row 384+ob*64+(r-64). Logical chunk clog = t*4 +
// kw*2 + hi (12 used of 16), stored at chunk clog ^ (r&7). Chunk = 8 f16 of
// i = st*32 + kw*16 + hi*8 + e, scaled by scale[l,t] (t = tap).
// ---------------------------------------------------------------------------
__global__ void wt_build_kernel(const float* __restrict__ v,
                                const float* __restrict__ scale,
                                _Float16* __restrict__ wimg) {
  int idx = blockIdx.x * 256 + threadIdx.x;
  if (idx >= 5 * 6 * 12 * 128 * 12) return;
  int clog = idx % 12;
  int r = (idx / 12) % 128;
  int st = (idx / (12 * 128)) % 12;
  int ob = (idx / (12 * 128 * 12)) % 6;
  int l = idx / (12 * 128 * 12 * 6);
  int t = clog >> 2, kw = (clog >> 1) & 1, hi = clog & 1;
  int og = (r < 64) ? (ob * 64 + r) : (384 + ob * 64 + (r - 64));
  int ibase = st * 32 + kw * 16 + hi * 8;
  float sc = scale[l * 3 + t];
  const float* vp = v + (((size_t)l * TW_ + og) * W_ + ibase) * KW + t;
  half8 hv;
#pragma unroll
  for (int e = 0; e < 8; ++e) hv[e] = (_Float16)(vp[e * 3] * sc);
  size_t dst = ((((size_t)l * 6 + ob) * 12 + st) * 128 + r) * 128 +
               ((clog ^ (r & 7)) * 8);
  *(half8*)(wimg + dst) = hv;
}

// ---------------------------------------------------------------------------
// Kernel 3: embedding. Writes h0 f32 (B,S,W) [conv input] if h0 != null and
// e f32 (B,W,S) [d_out e-half] if e_out != null.
// ---------------------------------------------------------------------------
__global__ __launch_bounds__(384) void embed_kernel(
    const int* __restrict__ x, const int* __restrict__ ngram_ids,
    const int* __restrict__ ngram_counts, const float* __restrict__ emb0,
    const float* __restrict__ tables, float* __restrict__ h0,
    float* __restrict__ e_out) {
  __shared__ float tile[W_][33];
  int b = blockIdx.y;
  int s0 = blockIdx.x * 32;
  int w = threadIdx.x;  // 0..383
  int n = w >> 7, t = w & 127;
  const float* tab = tables + (size_t)n * (V_ + 1) * E_ + t;

  for (int sl = 0; sl < 32; ++sl) {
    int s = s0 + sl;
    int xv = x[b * S_ + s];
    float val;
    if (xv < 4) {
      val = emb0[xv * W_ + w];
    } else {
      int base = (b * S_ + s) * N_ + n;
      int cnt = ngram_counts[base];
      const int* ids = ngram_ids + (size_t)base * L_;
      float acc = 0.f;
      for (int l = 0; l < cnt; ++l) {
        int id = ids[l];
        acc += tab[(size_t)id * E_];
      }
      val = acc / (float)cnt;
    }
    tile[w][sl] = val;
    if (h0) h0[((size_t)b * S_ + s) * W_ + w] = val;  // coalesced over w
  }
  if (e_out) {
    __syncthreads();
    for (int idx = threadIdx.x; idx < W_ * 32; idx += 384) {
      int wr = idx >> 5, sl = idx & 31;
      e_out[((size_t)b * W_ + wr) * S_ + s0 + sl] = tile[wr][sl];
    }
  }
}

// ---------------------------------------------------------------------------
// Kernel 4: fused conv1d(K=3) + bias + GLU + residual via f16 MFMA.
// Tile: BM=128 rows (64 'a' + 64 gate), BN=256 s. 4 waves = 2 Mhalf x 2 Nhalf;
// wave: Mfrag=2 (a row-band + its gate band -> GLU in-register), Nfrag=4.
// K staged in 12 chunks of 32 i. Ht: packed 2-s rows of 128B, XOR-swizzled
// (2-way = free). Wt: pre-swizzled image, staged by linear global_load_lds.
// XCD chunking: ob fastest within 8-col groups -> per-XCD L2 working set
// ~3.5MB (<4MiB), 6x reuse of each H column tile.
// ---------------------------------------------------------------------------
__global__ __launch_bounds__(256, 2) void conv_mfma_kernel(
    const float* __restrict__ hin,      // (B,S,W) f32
    float* __restrict__ hout,           // (B,S,W) f32, or (B,W,S) if final
    const _Float16* __restrict__ wimg,  // layer image base
    const float* __restrict__ bias,     // 768
    int final_layer) {
  __shared__ _Float16 Ht[129 * 64];    // 129 rows x 128 B
  __shared__ _Float16 Wts[128 * 128];  // 128 rows x 256 B
  __shared__ float Bs[128];

  const int bid = blockIdx.x;             // 0..767
  const int xcd = bid & 7, pos = bid >> 3;  // pos in [0,96)
  const int chunk = pos / 48, r48 = pos % 48;
  const int ob = r48 % 6;                 // fastest: 6 obs per column
  const int colw = r48 / 6;               // 0..7
  const int col = xcd * 8 + chunk * 64 + colw;  // bijective over [0,128)
  const int b = col >> 3;
  const int s0 = (col & 7) * 256;

  const int tid = threadIdx.x;
  const int wave = tid >> 6, lane = tid & 63;
  const int h = wave >> 1, q = wave & 1;
  const int l31 = lane & 31, hi = lane >> 5;

  if (tid < 128) {
    int og = (tid < 64) ? (ob * 64 + tid) : (384 + ob * 64 + (tid - 64));
    Bs[tid] = bias[og];
  }

  f32x16 acc0[4] = {{0.f}, {0.f}, {0.f}, {0.f}};
  f32x16 acc1[4] = {{0.f}, {0.f}, {0.f}, {0.f}};

  const int rowA0 = h * 32 + l31;  // a-band row in W tile
  const int rowA1 = rowA0 + 64;    // gate row

  for (int st = 0; st < 12; ++st) {
    __syncthreads();
    // ---- stage H: 258 s-rows (halo) x 4 chunks of 8 i, f32->f16 ----
    const int i0 = st * 32;
    for (int idx = tid; idx < 1032; idx += 256) {
      int sl = idx >> 2, g = idx & 3;
      int s = s0 + sl - 1;
      f32x4 v0 = {0.f, 0.f, 0.f, 0.f}, v1 = {0.f, 0.f, 0.f, 0.f};
      if (s >= 0 && s < S_) {
        const float* p = hin + ((size_t)b * S_ + s) * W_ + i0 + g * 8;
        v0 = *(const f32x4*)p;
        v1 = *(const f32x4*)(p + 4);
      }
      half8 hv;
#pragma unroll
      for (int j = 0; j < 4; ++j) {
        hv[j] = (_Float16)v0[j];
        hv[4 + j] = (_Float16)v1[j];
      }
      int rowp = sl >> 1;
      int slot = ((sl & 1) * 4 + g) ^ (rowp & 7);
      *(half8*)&Ht[rowp * 64 + slot * 8] = hv;
    }
    // ---- stage W: linear 32KB copy of pre-swizzled image ----
    const char* wsrc = (const char*)(wimg + ((size_t)(ob * 12 + st)) * 16384);
#pragma unroll
    for (int it = 0; it < 8; ++it) {
      gload_lds16(wsrc + it * 4096 + tid * 16,
                  ((char*)Wts) + it * 4096 + tid * 16);
    }
    __syncthreads();

    // ---- MFMA phase: 3 taps x 2 k16-windows x (2 M x 4 N) ----
#pragma unroll
    for (int t = 0; t < 3; ++t) {
#pragma unroll
      for (int kw = 0; kw < 2; ++kw) {
        int cA = t * 4 + kw * 2 + hi;
        half8 a0 = *(const half8*)&Wts[rowA0 * 128 + ((cA ^ (rowA0 & 7)) * 8)];
        half8 a1 = *(const half8*)&Wts[rowA1 * 128 + ((cA ^ (rowA1 & 7)) * 8)];
        half8 bf[4];
#pragma unroll
        for (int nf = 0; nf < 4; ++nf) {
          int sl = q * 128 + nf * 32 + l31 + t;
          int rowp = sl >> 1;
          int slot = ((sl & 1) * 4 + kw * 2 + hi) ^ (rowp & 7);
          bf[nf] = *(const half8*)&Ht[rowp * 64 + slot * 8];
        }
#pragma unroll
        for (int nf = 0; nf < 4; ++nf) {
          acc0[nf] =
              __builtin_amdgcn_mfma_f32_32x32x16_f16(a0, bf[nf], acc0[nf], 0, 0, 0);
          acc1[nf] =
              __builtin_amdgcn_mfma_f32_32x32x16_f16(a1, bf[nf], acc1[nf], 0, 0, 0);
        }
      }
    }
  }

  // ---- epilogue: bias + GLU + gm + residual ----
  const int obb = ob * 64 + h * 32;
#pragma unroll
  for (int nf = 0; nf < 4; ++nf) {
    int s = s0 + q * 128 + nf * 32 + l31;
    size_t row_in = ((size_t)b * S_ + s) * W_;
#pragma unroll
    for (int qd = 0; qd < 4; ++qd) {
      int rbase = qd * 8 + hi * 4;  // row32 base
      f32x4 res = *(const f32x4*)&hin[row_in + obb + rbase];
      f32x4 o4;
#pragma unroll
      for (int rr = 0; rr < 4; ++rr) {
        int r = qd * 4 + rr;
        float a = acc0[nf][r] + Bs[h * 32 + rbase + rr];
        float g = acc1[nf][r] + Bs[64 + h * 32 + rbase + rr];
        float y = a / (1.f + __expf(-g));
        y = y * GM_ + y * (1.0f - GM_);
        o4[rr] = (y + res[rr]) * SQRT_HALF_;
      }
      if (final_layer) {
#pragma unroll
        for (int rr = 0; rr < 4; ++rr)
          hout[((size_t)b * W_ + obb + rbase + rr) * S_ + s] = o4[rr];
      } else {
        *(f32x4*)&hout[row_in + obb + rbase] = o4;
      }
    }
  }
}

// ---------------------------------------------------------------------------
extern "C" void kernel_launch(void* const* d_in, const int* in_sizes, int n_in,
                              void* d_out, int out_size, void* d_ws,
                              size_t ws_size, hipStream_t stream) {
  const int* x = (const int*)d_in[0];
  const int* ngram_ids = (const int*)d_in[1];
  const int* ngram_counts = (const int*)d_in[2];
  const float* emb0 = (const float*)d_in[3];
  const float* tables = (const float*)d_in[4];
  const float* conv_v = (const float*)d_in[5];
  const float* conv_g = (const float*)d_in[6];
  const float* conv_b = (const float*)d_in[7];

  float* out_h = (float*)d_out;                 // final h (B,W,S); scratch earlier
  float* out_e = out_h + (size_t)B_ * W_ * S_;  // e (B,W,S)

  const size_t wimg_bytes = (size_t)5 * 6 * 12 * 128 * 128 * 2;  // 11,796,480
  const size_t hA_bytes = (size_t)B_ * S_ * W_ * 4;              // 50,331,648

  char* ws = (char*)d_ws;
  float* ws_scale = (float*)ws;  // 15 floats (+pad to 1 KB)

  // Path A: wimg + hA both fit in ws. Path B (tight ws): hA in ws, wimg
  // parked in the out_e region of d_out; e is (re)computed after the convs.
  const bool fits = ws_size >= 1024 + wimg_bytes + hA_bytes;
  _Float16* wimg = fits ? (_Float16*)(ws + 1024) : (_Float16*)out_e;
  float* hA = fits ? (float*)(ws + 1024 + wimg_bytes) : (float*)(ws + 1024);

  scale_kernel<<<LYR_ * KW, 256, 0, stream>>>(conv_v, conv_g, ws_scale);
  wt_build_kernel<<<(5 * 6 * 12 * 128 * 12 + 255) / 256, 256, 0, stream>>>(
      conv_v, ws_scale, wimg);
  embed_kernel<<<dim3(S_ / 32, B_), 384, 0, stream>>>(
      x, ngram_ids, ngram_counts, emb0, tables, hA, fits ? out_e : nullptr);

  // ping-pong: hA <-> d_out h-region (used as (B,S,W) scratch until final)
  const size_t lsz = (size_t)6 * 12 * 16384;  // halfs per layer image
  float* bufs[2] = {hA, out_h};
  for (int l = 0; l < LYR_; ++l) {
    const float* hin = bufs[(l & 1)];
    float* hout = bufs[(l & 1) ^ 1];
    conv_mfma_kernel<<<768, 256, 0, stream>>>(hin, hout, wimg + (size_t)l * lsz,
                                              conv_b + l * TW_,
                                              l == LYR_ - 1 ? 1 : 0);
  }
  if (!fits) {  // wimg (in out_e) no longer needed; write e last
    embed_kernel<<<dim3(S_ / 32, B_), 384, 0, stream>>>(
        x, ngram_ids, ngram_counts, emb0, tables, nullptr, out_e);
  }
}

// Round 7
// 1018.540 us; speedup vs baseline: 7.6015x; 1.4785x over previous
//
#include <hip/hip_runtime.h>
#include <cmath>

#define B_ 16
#define S_ 2048
#define N_ 3
#define E_ 128
#define V_ 50000
#define L_ 12
#define KW 3
#define LYR_ 5
#define W_ 384
#define TW_ 768

static constexpr float GM_ = 1.0f / 6.0f;  // 1/(2*ATTN_LAYERS)
static constexpr float SQRT_HALF_ = 0.7071067811865476f;

typedef _Float16 half8 __attribute__((ext_vector_type(8)));
typedef float f32x4 __attribute__((ext_vector_type(4)));
typedef float f32x16 __attribute__((ext_vector_type(16)));

__device__ inline void gload_lds16(const void* g, void* l) {
  __builtin_amdgcn_global_load_lds(
      (const __attribute__((address_space(1))) void*)g,
      (__attribute__((address_space(3))) void*)l, 16, 0, 0);
}

// ---------------------------------------------------------------------------
// Kernel 1a: weight-norm partial sums. 480 blocks (5 layers x 96 segs), each
// block covers 9216 contiguous floats; per-thread 36 floats (9x float4) with
// compile-time tap-phase split (idx%3). part[blk*3+k] = sum of v^2 for tap k.
// ---------------------------------------------------------------------------
__global__ __launch_bounds__(256) void scale_partial_kernel(
    const float* __restrict__ v, float* __restrict__ part) {
  const int blk = blockIdx.x;  // 0..479
  const int layer = blk / 96, seg = blk % 96;
  const float* p =
      v + (size_t)layer * (TW_ * W_ * KW) + seg * 9216 + threadIdx.x * 36;
  float a0 = 0.f, a1 = 0.f, a2 = 0.f;
#pragma unroll
  for (int gq = 0; gq < 3; ++gq) {
    f32x4 q0 = *(const f32x4*)(p + gq * 12);
    f32x4 q1 = *(const f32x4*)(p + gq * 12 + 4);
    f32x4 q2 = *(const f32x4*)(p + gq * 12 + 8);
    a0 += q0[0] * q0[0] + q0[3] * q0[3] + q1[2] * q1[2] + q2[1] * q2[1];
    a1 += q0[1] * q0[1] + q1[0] * q1[0] + q1[3] * q1[3] + q2[2] * q2[2];
    a2 += q0[2] * q0[2] + q1[1] * q1[1] + q2[0] * q2[0] + q2[3] * q2[3];
  }
  for (int off = 32; off > 0; off >>= 1) {
    a0 += __shfl_down(a0, off, 64);
    a1 += __shfl_down(a1, off, 64);
    a2 += __shfl_down(a2, off, 64);
  }
  __shared__ float red[4][3];
  int lane = threadIdx.x & 63, wv = threadIdx.x >> 6;
  if (lane == 0) { red[wv][0] = a0; red[wv][1] = a1; red[wv][2] = a2; }
  __syncthreads();
  if (threadIdx.x == 0) {
#pragma unroll
    for (int k = 0; k < 3; ++k)
      part[blk * 3 + k] = red[0][k] + red[1][k] + red[2][k] + red[3][k];
  }
}

// Kernel 1b: finish. scale[l*3+k] = g[l*3+k] / sqrt(sum over 96 partials).
__global__ void scale_finish_kernel(const float* __restrict__ part,
                                    const float* __restrict__ g,
                                    float* __restrict__ scale) {
  int tid = threadIdx.x;
  if (tid >= 240) return;
  int gi = tid >> 4, l16 = tid & 15;  // gi = layer*3+k
  int layer = gi / 3, k = gi % 3;
  float s = 0.f;
#pragma unroll
  for (int j = 0; j < 6; ++j)
    s += part[(layer * 96 + l16 * 6 + j) * 3 + k];
  for (int off = 8; off > 0; off >>= 1) s += __shfl_down(s, off, 16);
  if (l16 == 0) scale[gi] = g[gi] / sqrtf(s);
}

// ---------------------------------------------------------------------------
// Kernel 2: bake weights into pre-swizzled f16 images. layer_only < 0: all 5
// layers into full wimg; layer_only = l: just layer l into a 1-layer slot.
// Image (ob, st): 128 rows x 256B; row r<64 -> 'a' row ob*64+r, else gate
// row 384+ob*64+(r-64). Chunk clog = t*4+kw*2+hi stored at clog^(r&7);
// chunk = 8 f16 of i = st*32+kw*16+hi*8+e, scaled by scale[l,t].
// ---------------------------------------------------------------------------
__global__ void wt_build_kernel(const float* __restrict__ v,
                                const float* __restrict__ scale,
                                _Float16* __restrict__ wimg, int layer_only) {
  const int per_layer = 6 * 12 * 128 * 12;
  int idx = blockIdx.x * 256 + threadIdx.x;
  int tot = (layer_only >= 0) ? per_layer : 5 * per_layer;
  if (idx >= tot) return;
  int clog = idx % 12;
  int r = (idx / 12) % 128;
  int st = (idx / (12 * 128)) % 12;
  int ob = (idx / (12 * 128 * 12)) % 6;
  int l = (layer_only >= 0) ? layer_only : idx / per_layer;
  int t = clog >> 2, kw = (clog >> 1) & 1, hi = clog & 1;
  int og = (r < 64) ? (ob * 64 + r) : (384 + ob * 64 + (r - 64));
  int ibase = st * 32 + kw * 16 + hi * 8;
  float sc = scale[l * 3 + t];
  const float* vp = v + (((size_t)l * TW_ + og) * W_ + ibase) * KW + t;
  half8 hv;
#pragma unroll
  for (int e = 0; e < 8; ++e) hv[e] = (_Float16)(vp[e * 3] * sc);
  size_t img = (layer_only >= 0) ? (size_t)(ob * 12 + st)
                                 : (size_t)((l * 6 + ob) * 12 + st);
  size_t dst = (img * 128 + r) * 128 + ((clog ^ (r & 7)) * 8);
  *(half8*)(wimg + dst) = hv;
}

// ---------------------------------------------------------------------------
// Kernel 3: embedding. Writes h0 f32 (B,S,W) [conv input] if h0 != null and
// e f32 (B,W,S) [d_out e-half] if e_out != null.
// ---------------------------------------------------------------------------
__global__ __launch_bounds__(384) void embed_kernel(
    const int* __restrict__ x, const int* __restrict__ ngram_ids,
    const int* __restrict__ ngram_counts, const float* __restrict__ emb0,
    const float* __restrict__ tables, float* __restrict__ h0,
    float* __restrict__ e_out) {
  __shared__ float tile[W_][33];
  int b = blockIdx.y;
  int s0 = blockIdx.x * 32;
  int w = threadIdx.x;  // 0..383
  int n = w >> 7, t = w & 127;
  const float* tab = tables + (size_t)n * (V_ + 1) * E_ + t;

  for (int sl = 0; sl < 32; ++sl) {
    int s = s0 + sl;
    int xv = x[b * S_ + s];
    float val;
    if (xv < 4) {
      val = emb0[xv * W_ + w];
    } else {
      int base = (b * S_ + s) * N_ + n;
      int cnt = ngram_counts[base];
      const int* ids = ngram_ids + (size_t)base * L_;
      float acc = 0.f;
      for (int l = 0; l < cnt; ++l) {
        int id = ids[l];
        acc += tab[(size_t)id * E_];
      }
      val = acc / (float)cnt;
    }
    tile[w][sl] = val;
    if (h0) h0[((size_t)b * S_ + s) * W_ + w] = val;  // coalesced over w
  }
  if (e_out) {
    __syncthreads();
    for (int idx = threadIdx.x; idx < W_ * 32; idx += 384) {
      int wr = idx >> 5, sl = idx & 31;
      e_out[((size_t)b * W_ + wr) * S_ + s0 + sl] = tile[wr][sl];
    }
  }
}

// ---------------------------------------------------------------------------
// Kernel 4: fused conv1d(K=3) + bias + GLU + residual via f16 MFMA.
// Tile: BM=128 rows (64 'a' + 64 gate), BN=256 s. 4 waves = 2 Mhalf x 2 Nhalf;
// wave: Mfrag=2 (a row-band + its gate band -> GLU in-register), Nfrag=4.
// K staged in 12 chunks of 32 i. Ht: packed 2-s rows of 128B, XOR-swizzled
// (2-way = free). Wt: pre-swizzled image, staged by linear global_load_lds.
// XCD chunking: ob fastest within 8-col groups -> per-XCD L2 working set
// ~3.5MB (<4MiB), 6x reuse of each H column tile.
// ---------------------------------------------------------------------------
__global__ __launch_bounds__(256, 2) void conv_mfma_kernel(
    const float* __restrict__ hin,      // (B,S,W) f32
    float* __restrict__ hout,           // (B,S,W) f32, or (B,W,S) if final
    const _Float16* __restrict__ wimg,  // layer image base
    const float* __restrict__ bias,     // 768
    int final_layer) {
  __shared__ _Float16 Ht[129 * 64];    // 129 rows x 128 B
  __shared__ _Float16 Wts[128 * 128];  // 128 rows x 256 B
  __shared__ float Bs[128];

  const int bid = blockIdx.x;               // 0..767
  const int xcd = bid & 7, pos = bid >> 3;  // pos in [0,96)
  const int chunk = pos / 48, r48 = pos % 48;
  const int ob = r48 % 6;                   // fastest: 6 obs per column
  const int colw = r48 / 6;                 // 0..7
  const int col = xcd * 8 + chunk * 64 + colw;  // bijective over [0,128)
  const int b = col >> 3;
  const int s0 = (col & 7) * 256;

  const int tid = threadIdx.x;
  const int wave = tid >> 6, lane = tid & 63;
  const int h = wave >> 1, q = wave & 1;
  const int l31 = lane & 31, hi = lane >> 5;

  if (tid < 128) {
    int og = (tid < 64) ? (ob * 64 + tid) : (384 + ob * 64 + (tid - 64));
    Bs[tid] = bias[og];
  }

  f32x16 acc0[4] = {{0.f}, {0.f}, {0.f}, {0.f}};
  f32x16 acc1[4] = {{0.f}, {0.f}, {0.f}, {0.f}};

  const int rowA0 = h * 32 + l31;  // a-band row in W tile
  const int rowA1 = rowA0 + 64;    // gate row

  for (int st = 0; st < 12; ++st) {
    __syncthreads();
    // ---- stage H: 258 s-rows (halo) x 4 chunks of 8 i, f32->f16 ----
    const int i0 = st * 32;
    for (int idx = tid; idx < 1032; idx += 256) {
      int sl = idx >> 2, g = idx & 3;
      int s = s0 + sl - 1;
      f32x4 v0 = {0.f, 0.f, 0.f, 0.f}, v1 = {0.f, 0.f, 0.f, 0.f};
      if (s >= 0 && s < S_) {
        const float* p = hin + ((size_t)b * S_ + s) * W_ + i0 + g * 8;
        v0 = *(const f32x4*)p;
        v1 = *(const f32x4*)(p + 4);
      }
      half8 hv;
#pragma unroll
      for (int j = 0; j < 4; ++j) {
        hv[j] = (_Float16)v0[j];
        hv[4 + j] = (_Float16)v1[j];
      }
      int rowp = sl >> 1;
      int slot = ((sl & 1) * 4 + g) ^ (rowp & 7);
      *(half8*)&Ht[rowp * 64 + slot * 8] = hv;
    }
    // ---- stage W: linear 32KB copy of pre-swizzled image ----
    const char* wsrc = (const char*)(wimg + ((size_t)(ob * 12 + st)) * 16384);
#pragma unroll
    for (int it = 0; it < 8; ++it) {
      gload_lds16(wsrc + it * 4096 + tid * 16,
                  ((char*)Wts) + it * 4096 + tid * 16);
    }
    __syncthreads();

    // ---- MFMA phase: 3 taps x 2 k16-windows x (2 M x 4 N) ----
#pragma unroll
    for (int t = 0; t < 3; ++t) {
#pragma unroll
      for (int kw = 0; kw < 2; ++kw) {
        int cA = t * 4 + kw * 2 + hi;
        half8 a0 = *(const half8*)&Wts[rowA0 * 128 + ((cA ^ (rowA0 & 7)) * 8)];
        half8 a1 = *(const half8*)&Wts[rowA1 * 128 + ((cA ^ (rowA1 & 7)) * 8)];
        half8 bf[4];
#pragma unroll
        for (int nf = 0; nf < 4; ++nf) {
          int sl = q * 128 + nf * 32 + l31 + t;
          int rowp = sl >> 1;
          int slot = ((sl & 1) * 4 + kw * 2 + hi) ^ (rowp & 7);
          bf[nf] = *(const half8*)&Ht[rowp * 64 + slot * 8];
        }
#pragma unroll
        for (int nf = 0; nf < 4; ++nf) {
          acc0[nf] =
              __builtin_amdgcn_mfma_f32_32x32x16_f16(a0, bf[nf], acc0[nf], 0, 0, 0);
          acc1[nf] =
              __builtin_amdgcn_mfma_f32_32x32x16_f16(a1, bf[nf], acc1[nf], 0, 0, 0);
        }
      }
    }
  }

  // ---- epilogue: bias + GLU + gm + residual ----
  const int obb = ob * 64 + h * 32;
#pragma unroll
  for (int nf = 0; nf < 4; ++nf) {
    int s = s0 + q * 128 + nf * 32 + l31;
    size_t row_in = ((size_t)b * S_ + s) * W_;
#pragma unroll
    for (int qd = 0; qd < 4; ++qd) {
      int rbase = qd * 8 + hi * 4;  // row32 base
      f32x4 res = *(const f32x4*)&hin[row_in + obb + rbase];
      f32x4 o4;
#pragma unroll
      for (int rr = 0; rr < 4; ++rr) {
        int r = qd * 4 + rr;
        float a = acc0[nf][r] + Bs[h * 32 + rbase + rr];
        float g = acc1[nf][r] + Bs[64 + h * 32 + rbase + rr];
        float y = a / (1.f + __expf(-g));
        y = y * GM_ + y * (1.0f - GM_);
        o4[rr] = (y + res[rr]) * SQRT_HALF_;
      }
      if (final_layer) {
#pragma unroll
        for (int rr = 0; rr < 4; ++rr)
          hout[((size_t)b * W_ + obb + rbase + rr) * S_ + s] = o4[rr];
      } else {
        *(f32x4*)&hout[row_in + obb + rbase] = o4;
      }
    }
  }
}

// ---------------------------------------------------------------------------
extern "C" void kernel_launch(void* const* d_in, const int* in_sizes, int n_in,
                              void* d_out, int out_size, void* d_ws,
                              size_t ws_size, hipStream_t stream) {
  const int* x = (const int*)d_in[0];
  const int* ngram_ids = (const int*)d_in[1];
  const int* ngram_counts = (const int*)d_in[2];
  const float* emb0 = (const float*)d_in[3];
  const float* tables = (const float*)d_in[4];
  const float* conv_v = (const float*)d_in[5];
  const float* conv_g = (const float*)d_in[6];
  const float* conv_b = (const float*)d_in[7];

  float* out_h = (float*)d_out;                 // final h (B,W,S); scratch earlier
  float* out_e = out_h + (size_t)B_ * W_ * S_;  // e (B,W,S)

  const size_t HDR = 8192;
  const size_t wimg_bytes = (size_t)5 * 6 * 12 * 128 * 128 * 2;  // 11,796,480
  const size_t lyr_bytes = wimg_bytes / 5;                       // 2,359,296
  const size_t hA_bytes = (size_t)B_ * S_ * W_ * 4;              // 50,331,648
  const size_t lsz = (size_t)6 * 12 * 16384;  // halfs per layer image

  char* ws = (char*)d_ws;
  float* ws_scale = (float*)ws;          // 15 floats
  float* ws_part = (float*)(ws + 256);   // 480*3 floats

  // mode 0: full wimg + hA in ws. mode 1: hA + per-layer slot in ws.
  // mode 2: hA in ws, wimg parked in out_e, e recomputed after convs.
  int mode;
  if (ws_size >= HDR + wimg_bytes + hA_bytes) mode = 0;
  else if (ws_size >= HDR + hA_bytes + lyr_bytes) mode = 1;
  else mode = 2;

  _Float16* wimg = (mode == 0) ? (_Float16*)(ws + HDR)
                   : (mode == 1) ? (_Float16*)(ws + HDR + hA_bytes)
                                 : (_Float16*)out_e;
  float* hA = (mode == 0) ? (float*)(ws + HDR + wimg_bytes) : (float*)(ws + HDR);

  scale_partial_kernel<<<480, 256, 0, stream>>>(conv_v, ws_part);
  scale_finish_kernel<<<1, 256, 0, stream>>>(ws_part, conv_g, ws_scale);
  if (mode != 1)
    wt_build_kernel<<<(5 * 6 * 12 * 128 * 12 + 255) / 256, 256, 0, stream>>>(
        conv_v, ws_scale, wimg, -1);
  embed_kernel<<<dim3(S_ / 32, B_), 384, 0, stream>>>(
      x, ngram_ids, ngram_counts, emb0, tables, hA, mode == 2 ? nullptr : out_e);

  // ping-pong: hA <-> d_out h-region (used as (B,S,W) scratch until final)
  float* bufs[2] = {hA, out_h};
  for (int l = 0; l < LYR_; ++l) {
    const float* hin = bufs[(l & 1)];
    float* hout = bufs[(l & 1) ^ 1];
    if (mode == 1)
      wt_build_kernel<<<(6 * 12 * 128 * 12 + 255) / 256, 256, 0, stream>>>(
          conv_v, ws_scale, wimg, l);
    conv_mfma_kernel<<<768, 256, 0, stream>>>(
        hin, hout, (mode == 1) ? wimg : wimg + (size_t)l * lsz,
        conv_b + l * TW_, l == LYR_ - 1 ? 1 : 0);
  }
  if (mode == 2) {  // wimg (in out_e) no longer needed; write e last
    embed_kernel<<<dim3(S_ / 32, B_), 384, 0, stream>>>(
        x, ngram_ids, ngram_counts, emb0, tables, nullptr, out_e);
  }
}